// Round 7
// baseline (2599.503 us; speedup 1.0000x reference)
//
#include <hip/hip_runtime.h>
#include <hip/hip_bf16.h>
#include <math.h>

#define N 8192
#define F 133
#define FP 136
#define H 256
#define MF 200
#define RH 512
#define DEPTH 3
#define MAXDEG 128
#define DROWS 16           // rows per k_depth block
#define DBLOCKS (N / DROWS)

#define PD_ITERS 20
#define PS_ITERS 5
#define PI_ITERS 24

typedef unsigned short bfu;

static __device__ __forceinline__ bfu f2bf(float f) {
    unsigned u = __builtin_bit_cast(unsigned, f);
    u = (u + 0x7fff + ((u >> 16) & 1)) >> 16;   // RNE, finite inputs
    return (bfu)u;
}
static __device__ __forceinline__ float bf2f(bfu b) {
    unsigned u = (unsigned)b << 16;
    return __builtin_bit_cast(float, u);
}

// ---------------- sparse index build: wave-per-row ballot compaction ----------------
__global__ __launch_bounds__(256) void k_scan(const float4* __restrict__ A4,
                                              int* __restrict__ cnt,
                                              int* __restrict__ colidx) {
    const int wave = threadIdx.x >> 6;
    const int lane = threadIdx.x & 63;
    const int row = blockIdx.x * 4 + wave;
    const float4* rowp = A4 + (size_t)row * (N / 4);
    const unsigned long long lmask = (1ull << lane) - 1ull;
    int base = 0;
    int* rowout = colidx + row * MAXDEG;
    for (int it = 0; it < N / 4 / 64; ++it) {
        float4 v = rowp[it * 64 + lane];
        int col0 = (it * 64 + lane) * 4;
        float vv[4] = {v.x, v.y, v.z, v.w};
#pragma unroll
        for (int c = 0; c < 4; ++c) {
            bool nz = (vv[c] != 0.0f);
            unsigned long long m = __ballot(nz);
            if (nz) {
                int pos = base + __popcll(m & lmask);
                if (pos < MAXDEG) rowout[pos] = col0 + c;
            }
            base += __popcll(m);
        }
    }
    if (lane == 0) cnt[row] = base < MAXDEG ? base : MAXDEG;
}

// ---------------- h0 = X @ W_in + b_in  -> bf16 ----------------
__global__ __launch_bounds__(256) void k_in(const float* __restrict__ X,
                                            const float* __restrict__ W,
                                            const float* __restrict__ b,
                                            bfu* __restrict__ hout) {
    __shared__ float xs[32][FP];
    const int t = threadIdx.x;
    const int row0 = blockIdx.x * 32;
    for (int i = t; i < 32 * F; i += 256) {
        int r = i / F, f = i - r * F;
        xs[r][f] = X[(row0 + r) * F + f];
    }
    __syncthreads();
    float acc[32];
#pragma unroll
    for (int r = 0; r < 32; ++r) acc[r] = 0.f;
    for (int f = 0; f < 132; f += 4) {
        float w0 = W[(f + 0) * H + t];
        float w1 = W[(f + 1) * H + t];
        float w2 = W[(f + 2) * H + t];
        float w3 = W[(f + 3) * H + t];
#pragma unroll
        for (int r = 0; r < 32; ++r) {
            float4 xv = *reinterpret_cast<const float4*>(&xs[r][f]);
            acc[r] = fmaf(xv.x, w0, acc[r]);
            acc[r] = fmaf(xv.y, w1, acc[r]);
            acc[r] = fmaf(xv.z, w2, acc[r]);
            acc[r] = fmaf(xv.w, w3, acc[r]);
        }
    }
    {
        float w0 = W[132 * H + t];
#pragma unroll
        for (int r = 0; r < 32; ++r) acc[r] = fmaf(xs[r][132], w0, acc[r]);
    }
    float bb = b[t];
#pragma unroll
    for (int r = 0; r < 32; ++r) hout[(row0 + r) * H + t] = f2bf(acc[r] + bb);
}

// ---------------- attention scores for h0 ----------------
__global__ __launch_bounds__(256) void k_scores(const bfu* __restrict__ h,
                                                const float* __restrict__ Watt,
                                                float* __restrict__ s_nei,
                                                float* __restrict__ s_self) {
    const int lane = threadIdx.x & 63;
    const int wave = threadIdx.x >> 6;
    const int row = blockIdx.x * 4 + wave;
    const ushort4 hv = *reinterpret_cast<const ushort4*>(&h[row * H + lane * 4]);
    const float4 wn = *reinterpret_cast<const float4*>(&Watt[lane * 4]);
    const float4 ws = *reinterpret_cast<const float4*>(&Watt[H + lane * 4]);
    float h0 = bf2f(hv.x), h1 = bf2f(hv.y), h2 = bf2f(hv.z), h3 = bf2f(hv.w);
    float an = h0 * wn.x + h1 * wn.y + h2 * wn.z + h3 * wn.w;
    float as = h0 * ws.x + h1 * ws.y + h2 * ws.z + h3 * ws.w;
    for (int off = 32; off > 0; off >>= 1) {
        an += __shfl_down(an, off);
        as += __shfl_down(as, off);
    }
    if (lane == 0) { s_nei[row] = an; s_self[row] = as; }
}

// ---------------- fused depth, 16 rows/block, 512 blocks ----------------
template <bool LAST>
__global__ __launch_bounds__(256) void k_depth(
    const bfu* __restrict__ hin, bfu* __restrict__ hout,
    const int* __restrict__ cnt, const int* __restrict__ colidx,
    const float* __restrict__ snei_in, const float* __restrict__ sself_in,
    float* __restrict__ snei_out, float* __restrict__ sself_out,
    const float* __restrict__ Wn, const float* __restrict__ bn,
    const float* __restrict__ Watt, const float* __restrict__ b_att,
    float* __restrict__ part) {
    __shared__ float hgT[64 * 68];
    __shared__ float wls[DROWS * 128];
    __shared__ int   jls[DROWS * 128];
    __shared__ float csred[4 * 256];
    __shared__ float sselfL[DROWS];
    __shared__ int   ncnt[DROWS];
    const int t = threadIdx.x;
    const int w = t >> 6, l = t & 63;
    const int R0 = blockIdx.x * DROWS;

    if (t < DROWS) { ncnt[t] = cnt[R0 + t]; sselfL[t] = sself_in[R0 + t] + b_att[0]; }
    __syncthreads();
#pragma unroll
    for (int rep = 0; rep < 8; ++rep) {
        int idx = t + rep * 256;
        int r = idx >> 7, k = idx & 127;
        if (k < ncnt[r]) {
            int j = colidx[(R0 + r) * MAXDEG + k];
            jls[idx] = j;
            wls[idx] = 1.f / (1.f + __expf(-(sselfL[r] + snei_in[j])));
        }
    }
    __syncthreads();
    {
#define GSTEP(u, sx, sy, sz, sw)                                                  \
        { int ju = jls[r * 128 + k + u]; float wv = wls[r * 128 + k + u];         \
          ushort4 hv = *reinterpret_cast<const ushort4*>(&hin[ju * 256 + (l << 2)]); \
          sx = fmaf(wv, bf2f(hv.x), sx); sy = fmaf(wv, bf2f(hv.y), sy);           \
          sz = fmaf(wv, bf2f(hv.z), sz); sw = fmaf(wv, bf2f(hv.w), sw); }
        for (int rr = 0; rr < 4; ++rr) {
            int r = w * 4 + rr;
            int n = ncnt[r];
            float x0=0,y0=0,z0=0,w0=0, x1=0,y1=0,z1=0,w1=0;
            float x2=0,y2=0,z2=0,w2=0, x3=0,y3=0,z3=0,w3=0;
            float x4=0,y4=0,z4=0,w4=0, x5=0,y5=0,z5=0,w5=0;
            float x6=0,y6=0,z6=0,w6=0, x7=0,y7=0,z7=0,w7=0;
            int k = 0;
            for (; k + 8 <= n; k += 8) {
                GSTEP(0,x0,y0,z0,w0) GSTEP(1,x1,y1,z1,w1)
                GSTEP(2,x2,y2,z2,w2) GSTEP(3,x3,y3,z3,w3)
                GSTEP(4,x4,y4,z4,w4) GSTEP(5,x5,y5,z5,w5)
                GSTEP(6,x6,y6,z6,w6) GSTEP(7,x7,y7,z7,w7)
            }
            for (; k < n; ++k) { GSTEP(0,x0,y0,z0,w0) }
            float4 st;
            st.x = ((x0+x1)+(x2+x3)) + ((x4+x5)+(x6+x7));
            st.y = ((y0+y1)+(y2+y3)) + ((y4+y5)+(y6+y7));
            st.z = ((z0+z1)+(z2+z3)) + ((z4+z5)+(z6+z7));
            st.w = ((w0+w1)+(w2+w3)) + ((w4+w5)+(w6+w7));
            *reinterpret_cast<float4*>(&hgT[l * 68 + r * 4]) = st;
        }
#undef GSTEP
    }
    __syncthreads();
    float acc[4][4];
#pragma unroll
    for (int i = 0; i < 4; ++i)
#pragma unroll
        for (int j = 0; j < 4; ++j) acc[i][j] = 0.f;
    const int c0 = l << 2;
#pragma unroll 2
    for (int k4 = 0; k4 < 64; ++k4) {
        const float* hp = &hgT[k4 * 68 + 16 * w];
#pragma unroll
        for (int ki = 0; ki < 4; ++ki) {
            int kk = k4 * 4 + ki;
            float4 wv = *reinterpret_cast<const float4*>(&Wn[kk * 256 + c0]);
            float a0 = hp[0 * 4 + ki];
            float a1 = hp[1 * 4 + ki];
            float a2 = hp[2 * 4 + ki];
            float a3 = hp[3 * 4 + ki];
            acc[0][0] = fmaf(a0, wv.x, acc[0][0]); acc[0][1] = fmaf(a0, wv.y, acc[0][1]);
            acc[0][2] = fmaf(a0, wv.z, acc[0][2]); acc[0][3] = fmaf(a0, wv.w, acc[0][3]);
            acc[1][0] = fmaf(a1, wv.x, acc[1][0]); acc[1][1] = fmaf(a1, wv.y, acc[1][1]);
            acc[1][2] = fmaf(a1, wv.z, acc[1][2]); acc[1][3] = fmaf(a1, wv.w, acc[1][3]);
            acc[2][0] = fmaf(a2, wv.x, acc[2][0]); acc[2][1] = fmaf(a2, wv.y, acc[2][1]);
            acc[2][2] = fmaf(a2, wv.z, acc[2][2]); acc[2][3] = fmaf(a2, wv.w, acc[2][3]);
            acc[3][0] = fmaf(a3, wv.x, acc[3][0]); acc[3][1] = fmaf(a3, wv.y, acc[3][1]);
            acc[3][2] = fmaf(a3, wv.z, acc[3][2]); acc[3][3] = fmaf(a3, wv.w, acc[3][3]);
        }
    }
    const float4 bv = *reinterpret_cast<const float4*>(&bn[c0]);
    float4 wanv, wasv;
    if (!LAST) {
        wanv = *reinterpret_cast<const float4*>(&Watt[c0]);
        wasv = *reinterpret_cast<const float4*>(&Watt[H + c0]);
    }
    float cs0 = 0.f, cs1 = 0.f, cs2 = 0.f, cs3 = 0.f;
#pragma unroll
    for (int i = 0; i < 4; ++i) {
        float v0 = acc[i][0] + bv.x; v0 = v0 > 0.f ? v0 : 0.f;
        float v1 = acc[i][1] + bv.y; v1 = v1 > 0.f ? v1 : 0.f;
        float v2 = acc[i][2] + bv.z; v2 = v2 > 0.f ? v2 : 0.f;
        float v3 = acc[i][3] + bv.w; v3 = v3 > 0.f ? v3 : 0.f;
        ushort4 o; o.x = f2bf(v0); o.y = f2bf(v1); o.z = f2bf(v2); o.w = f2bf(v3);
        *reinterpret_cast<ushort4*>(&hout[(R0 + w * 4 + i) * H + c0]) = o;
        if (!LAST) {
            float pn = v0 * wanv.x + v1 * wanv.y + v2 * wanv.z + v3 * wanv.w;
            float ps = v0 * wasv.x + v1 * wasv.y + v2 * wasv.z + v3 * wasv.w;
#pragma unroll
            for (int off = 32; off > 0; off >>= 1) {
                pn += __shfl_xor(pn, off);
                ps += __shfl_xor(ps, off);
            }
            if (l == 0) {
                snei_out[R0 + w * 4 + i] = pn;
                sself_out[R0 + w * 4 + i] = ps;
            }
        } else {
            cs0 += v0; cs1 += v1; cs2 += v2; cs3 += v3;
        }
    }
    if (LAST) {
        csred[w * 256 + c0 + 0] = cs0;
        csred[w * 256 + c0 + 1] = cs1;
        csred[w * 256 + c0 + 2] = cs2;
        csred[w * 256 + c0 + 3] = cs3;
        __syncthreads();
        part[blockIdx.x * H + t] =
            (csred[t] + csred[256 + t]) + (csred[512 + t] + csred[768 + t]);
    }
}

// ================= DIAGNOSTIC PROBES (scratch-only writes) =================
// Each loops its kernel body with a rotated block->work mapping so one
// dispatch exceeds the ~163us harness fills and shows up in top-5 with
// counters. Work per iteration is identical to the real kernel.

__global__ __launch_bounds__(256) void p_scan(const float4* __restrict__ A4,
                                              int* __restrict__ cnt,
                                              int* __restrict__ colidx) {
    const int wave = threadIdx.x >> 6;
    const int lane = threadIdx.x & 63;
    const unsigned long long lmask = (1ull << lane) - 1ull;
#pragma unroll 1
    for (int it2 = 0; it2 < PS_ITERS; ++it2) {
        const int row = ((blockIdx.x + it2 * 911) % (N / 4)) * 4 + wave;
        const float4* rowp = A4 + (size_t)row * (N / 4);
        int base = 0;
        int* rowout = colidx + row * MAXDEG;
        for (int it = 0; it < N / 4 / 64; ++it) {
            float4 v = rowp[it * 64 + lane];
            int col0 = (it * 64 + lane) * 4;
            float vv[4] = {v.x, v.y, v.z, v.w};
#pragma unroll
            for (int c = 0; c < 4; ++c) {
                bool nz = (vv[c] != 0.0f);
                unsigned long long m = __ballot(nz);
                if (nz) {
                    int pos = base + __popcll(m & lmask);
                    if (pos < MAXDEG) rowout[pos] = col0 + c;
                }
                base += __popcll(m);
            }
        }
        if (lane == 0) cnt[row] = base < MAXDEG ? base : MAXDEG;
    }
}

__global__ __launch_bounds__(256) void p_in(const float* __restrict__ X,
                                            const float* __restrict__ W,
                                            const float* __restrict__ b,
                                            bfu* __restrict__ hout) {
    __shared__ float xs[32][FP];
    const int t = threadIdx.x;
#pragma unroll 1
    for (int it = 0; it < PI_ITERS; ++it) {
        const int row0 = ((blockIdx.x + it * 97) % (N / 32)) * 32;
        __syncthreads();
        for (int i = t; i < 32 * F; i += 256) {
            int r = i / F, f = i - r * F;
            xs[r][f] = X[(row0 + r) * F + f];
        }
        __syncthreads();
        float acc[32];
#pragma unroll
        for (int r = 0; r < 32; ++r) acc[r] = 0.f;
        for (int f = 0; f < 132; f += 4) {
            float w0 = W[(f + 0) * H + t];
            float w1 = W[(f + 1) * H + t];
            float w2 = W[(f + 2) * H + t];
            float w3 = W[(f + 3) * H + t];
#pragma unroll
            for (int r = 0; r < 32; ++r) {
                float4 xv = *reinterpret_cast<const float4*>(&xs[r][f]);
                acc[r] = fmaf(xv.x, w0, acc[r]);
                acc[r] = fmaf(xv.y, w1, acc[r]);
                acc[r] = fmaf(xv.z, w2, acc[r]);
                acc[r] = fmaf(xv.w, w3, acc[r]);
            }
        }
        {
            float w0 = W[132 * H + t];
#pragma unroll
            for (int r = 0; r < 32; ++r) acc[r] = fmaf(xs[r][132], w0, acc[r]);
        }
        float bb = b[t];
#pragma unroll
        for (int r = 0; r < 32; ++r) hout[(row0 + r) * H + t] = f2bf(acc[r] + bb);
    }
}

__global__ __launch_bounds__(256) void p_depth(
    const bfu* __restrict__ hin, bfu* __restrict__ hout,
    const int* __restrict__ cnt, const int* __restrict__ colidx,
    const float* __restrict__ snei_in, const float* __restrict__ sself_in,
    float* __restrict__ snei_out, float* __restrict__ sself_out,
    const float* __restrict__ Wn, const float* __restrict__ bn,
    const float* __restrict__ Watt, const float* __restrict__ b_att) {
    __shared__ float hgT[64 * 68];
    __shared__ float wls[DROWS * 128];
    __shared__ int   jls[DROWS * 128];
    __shared__ float sselfL[DROWS];
    __shared__ int   ncnt[DROWS];
    const int t = threadIdx.x;
    const int w = t >> 6, l = t & 63;
#pragma unroll 1
    for (int it = 0; it < PD_ITERS; ++it) {
        const int R0 = ((blockIdx.x + it * 131) % DBLOCKS) * DROWS;
        __syncthreads();
        if (t < DROWS) { ncnt[t] = cnt[R0 + t]; sselfL[t] = sself_in[R0 + t] + b_att[0]; }
        __syncthreads();
#pragma unroll
        for (int rep = 0; rep < 8; ++rep) {
            int idx = t + rep * 256;
            int r = idx >> 7, k = idx & 127;
            if (k < ncnt[r]) {
                int j = colidx[(R0 + r) * MAXDEG + k];
                jls[idx] = j;
                wls[idx] = 1.f / (1.f + __expf(-(sselfL[r] + snei_in[j])));
            }
        }
        __syncthreads();
        {
#define GSTEP(u, sx, sy, sz, sw)                                                  \
            { int ju = jls[r * 128 + k + u]; float wv = wls[r * 128 + k + u];     \
              ushort4 hv = *reinterpret_cast<const ushort4*>(&hin[ju * 256 + (l << 2)]); \
              sx = fmaf(wv, bf2f(hv.x), sx); sy = fmaf(wv, bf2f(hv.y), sy);       \
              sz = fmaf(wv, bf2f(hv.z), sz); sw = fmaf(wv, bf2f(hv.w), sw); }
            for (int rr = 0; rr < 4; ++rr) {
                int r = w * 4 + rr;
                int n = ncnt[r];
                float x0=0,y0=0,z0=0,w0=0, x1=0,y1=0,z1=0,w1=0;
                float x2=0,y2=0,z2=0,w2=0, x3=0,y3=0,z3=0,w3=0;
                float x4=0,y4=0,z4=0,w4=0, x5=0,y5=0,z5=0,w5=0;
                float x6=0,y6=0,z6=0,w6=0, x7=0,y7=0,z7=0,w7=0;
                int k = 0;
                for (; k + 8 <= n; k += 8) {
                    GSTEP(0,x0,y0,z0,w0) GSTEP(1,x1,y1,z1,w1)
                    GSTEP(2,x2,y2,z2,w2) GSTEP(3,x3,y3,z3,w3)
                    GSTEP(4,x4,y4,z4,w4) GSTEP(5,x5,y5,z5,w5)
                    GSTEP(6,x6,y6,z6,w6) GSTEP(7,x7,y7,z7,w7)
                }
                for (; k < n; ++k) { GSTEP(0,x0,y0,z0,w0) }
                float4 st;
                st.x = ((x0+x1)+(x2+x3)) + ((x4+x5)+(x6+x7));
                st.y = ((y0+y1)+(y2+y3)) + ((y4+y5)+(y6+y7));
                st.z = ((z0+z1)+(z2+z3)) + ((z4+z5)+(z6+z7));
                st.w = ((w0+w1)+(w2+w3)) + ((w4+w5)+(w6+w7));
                *reinterpret_cast<float4*>(&hgT[l * 68 + r * 4]) = st;
            }
#undef GSTEP
        }
        __syncthreads();
        float acc[4][4];
#pragma unroll
        for (int i = 0; i < 4; ++i)
#pragma unroll
            for (int j = 0; j < 4; ++j) acc[i][j] = 0.f;
        const int c0 = l << 2;
#pragma unroll 2
        for (int k4 = 0; k4 < 64; ++k4) {
            const float* hp = &hgT[k4 * 68 + 16 * w];
#pragma unroll
            for (int ki = 0; ki < 4; ++ki) {
                int kk = k4 * 4 + ki;
                float4 wv = *reinterpret_cast<const float4*>(&Wn[kk * 256 + c0]);
                float a0 = hp[0 * 4 + ki];
                float a1 = hp[1 * 4 + ki];
                float a2 = hp[2 * 4 + ki];
                float a3 = hp[3 * 4 + ki];
                acc[0][0] = fmaf(a0, wv.x, acc[0][0]); acc[0][1] = fmaf(a0, wv.y, acc[0][1]);
                acc[0][2] = fmaf(a0, wv.z, acc[0][2]); acc[0][3] = fmaf(a0, wv.w, acc[0][3]);
                acc[1][0] = fmaf(a1, wv.x, acc[1][0]); acc[1][1] = fmaf(a1, wv.y, acc[1][1]);
                acc[1][2] = fmaf(a1, wv.z, acc[1][2]); acc[1][3] = fmaf(a1, wv.w, acc[1][3]);
                acc[2][0] = fmaf(a2, wv.x, acc[2][0]); acc[2][1] = fmaf(a2, wv.y, acc[2][1]);
                acc[2][2] = fmaf(a2, wv.z, acc[2][2]); acc[2][3] = fmaf(a2, wv.w, acc[2][3]);
                acc[3][0] = fmaf(a3, wv.x, acc[3][0]); acc[3][1] = fmaf(a3, wv.y, acc[3][1]);
                acc[3][2] = fmaf(a3, wv.z, acc[3][2]); acc[3][3] = fmaf(a3, wv.w, acc[3][3]);
            }
        }
        const float4 bv = *reinterpret_cast<const float4*>(&bn[c0]);
        const float4 wanv = *reinterpret_cast<const float4*>(&Watt[c0]);
        const float4 wasv = *reinterpret_cast<const float4*>(&Watt[H + c0]);
#pragma unroll
        for (int i = 0; i < 4; ++i) {
            float v0 = acc[i][0] + bv.x; v0 = v0 > 0.f ? v0 : 0.f;
            float v1 = acc[i][1] + bv.y; v1 = v1 > 0.f ? v1 : 0.f;
            float v2 = acc[i][2] + bv.z; v2 = v2 > 0.f ? v2 : 0.f;
            float v3 = acc[i][3] + bv.w; v3 = v3 > 0.f ? v3 : 0.f;
            ushort4 o; o.x = f2bf(v0); o.y = f2bf(v1); o.z = f2bf(v2); o.w = f2bf(v3);
            *reinterpret_cast<ushort4*>(&hout[(R0 + w * 4 + i) * H + c0]) = o;
            float pn = v0 * wanv.x + v1 * wanv.y + v2 * wanv.z + v3 * wanv.w;
            float ps = v0 * wasv.x + v1 * wasv.y + v2 * wasv.z + v3 * wasv.w;
#pragma unroll
            for (int off = 32; off > 0; off >>= 1) {
                pn += __shfl_xor(pn, off);
                ps += __shfl_xor(ps, off);
            }
            if (l == 0) {
                snei_out[R0 + w * 4 + i] = pn;
                sself_out[R0 + w * 4 + i] = ps;
            }
        }
    }
}

// ---------------- readout layer 1 ----------------
__global__ __launch_bounds__(256) void k_ro1(const float* __restrict__ part,
                                             const float* __restrict__ mol,
                                             const float* __restrict__ W,
                                             const float* __restrict__ b,
                                             float* __restrict__ out) {
    __shared__ float xin[H + MF];
    __shared__ float red[256];
    const int t = threadIdx.x;
    {
        float s0 = 0.f, s1 = 0.f, s2 = 0.f, s3 = 0.f;
        for (int bb = 0; bb < DBLOCKS; bb += 4) {
            s0 += part[(bb + 0) * H + t];
            s1 += part[(bb + 1) * H + t];
            s2 += part[(bb + 2) * H + t];
            s3 += part[(bb + 3) * H + t];
        }
        xin[t] = (s0 + s1) + (s2 + s3);
    }
    if (t < MF) xin[H + t] = mol[t];
    __syncthreads();
    const int o = blockIdx.x * 64 + (t & 63);
    const int kg = t >> 6;
    float acc = 0.f;
    for (int k = kg; k < H + MF; k += 4) acc = fmaf(xin[k], W[k * RH + o], acc);
    red[t] = acc;
    __syncthreads();
    if (t < 64) {
        float v = red[t] + red[t + 64] + red[t + 128] + red[t + 192] + b[o];
        out[o] = v > 0.f ? v : 0.f;
    }
}

// ---------------- readout hidden layer ----------------
__global__ __launch_bounds__(256) void k_ro_hid(const float* __restrict__ g,
                                                const float* __restrict__ W,
                                                const float* __restrict__ b,
                                                float* __restrict__ out) {
    __shared__ float xin[RH];
    __shared__ float red[256];
    const int t = threadIdx.x;
    xin[t] = g[t];
    xin[t + 256] = g[t + 256];
    __syncthreads();
    const int o = blockIdx.x * 64 + (t & 63);
    const int kg = t >> 6;
    float acc = 0.f;
    for (int k = kg; k < RH; k += 4) acc = fmaf(xin[k], W[k * RH + o], acc);
    red[t] = acc;
    __syncthreads();
    if (t < 64) {
        float v = red[t] + red[t + 64] + red[t + 128] + red[t + 192] + b[o];
        out[o] = v > 0.f ? v : 0.f;
    }
}

// ---------------- final dot ----------------
__global__ __launch_bounds__(256) void k_out(const float* __restrict__ g,
                                             const float* __restrict__ W,
                                             const float* __restrict__ bo,
                                             float* __restrict__ out) {
    __shared__ float red[256];
    int t = threadIdx.x;
    red[t] = g[t] * W[t] + g[t + 256] * W[t + 256];
    __syncthreads();
    for (int s = 128; s > 0; s >>= 1) {
        if (t < s) red[t] += red[t + s];
        __syncthreads();
    }
    if (t == 0) out[0] = red[0] + bo[0];
}

extern "C" void kernel_launch(void* const* d_in, const int* in_sizes, int n_in,
                              void* d_out, int out_size, void* d_ws, size_t ws_size,
                              hipStream_t stream) {
    const float* A        = (const float*)d_in[0];
    const float* X        = (const float*)d_in[1];
    const float* mol      = (const float*)d_in[2];
    const float* W_in     = (const float*)d_in[3];
    const float* b_in     = (const float*)d_in[4];
    const float* W_att    = (const float*)d_in[5];
    const float* b_att    = (const float*)d_in[6];
    const float* W_node   = (const float*)d_in[7];
    const float* b_node   = (const float*)d_in[8];
    const float* W_ro_in  = (const float*)d_in[9];
    const float* b_ro_in  = (const float*)d_in[10];
    const float* W_ro_hid = (const float*)d_in[11];
    const float* b_ro_hid = (const float*)d_in[12];
    const float* W_out    = (const float*)d_in[13];
    const float* b_out    = (const float*)d_in[14];

    char* ws = (char*)d_ws;
    bfu*   hb_a   = (bfu*)  (ws);                        // 4 MB
    bfu*   hb_b   = (bfu*)  (ws + 4194304);              // 4 MB
    int*   colidx = (int*)  (ws + 8388608);              // 4 MB
    int*   cnt    = (int*)  (ws + 12582912);             // 32 KB
    float* snei_a = (float*)(ws + 12615680);             // 32 KB
    float* sself_a= (float*)(ws + 12648448);             // 32 KB
    float* snei_b = (float*)(ws + 12681216);             // 32 KB
    float* sself_b= (float*)(ws + 12713984);             // 32 KB
    float* part   = (float*)(ws + 12746752);             // 512 KB
    float* g1     = (float*)(ws + 13271040);             // 2 KB
    float* g2     = (float*)(ws + 13273088);             // 2 KB
    float* g3     = (float*)(ws + 13275136);             // 2 KB
    // probe scratch
    bfu*   hb_s   = (bfu*)  (ws + 16777216);             // 4 MB
    float* snei_s = (float*)(ws + 20971520);             // 32 KB
    float* sself_s= (float*)(ws + 21004288);             // 32 KB
    int*   cnt_s  = (int*)  (ws + 21037056);             // 32 KB
    int*   colidx_s=(int*)  (ws + 21069824);             // 4 MB
    bfu*   h0_s   = (bfu*)  (ws + 25264128);             // 4 MB

    k_scan<<<N / 4, 256, 0, stream>>>((const float4*)A, cnt, colidx);
    k_in<<<N / 32, 256, 0, stream>>>(X, W_in, b_in, hb_a);
    k_scores<<<N / 4, 256, 0, stream>>>(hb_a, W_att, snei_a, sself_a);

    k_depth<false><<<DBLOCKS, 256, 0, stream>>>(
        hb_a, hb_b, cnt, colidx, snei_a, sself_a, snei_b, sself_b,
        W_node + 0 * H * H, b_node + 0 * H, W_att, b_att, nullptr);
    k_depth<false><<<DBLOCKS, 256, 0, stream>>>(
        hb_b, hb_a, cnt, colidx, snei_b, sself_b, snei_a, sself_a,
        W_node + 1 * H * H, b_node + 1 * H, W_att, b_att, nullptr);
    k_depth<true><<<DBLOCKS, 256, 0, stream>>>(
        hb_a, hb_b, cnt, colidx, snei_a, sself_a, nullptr, nullptr,
        W_node + 2 * H * H, b_node + 2 * H, W_att, b_att, part);

    k_ro1<<<RH / 64, 256, 0, stream>>>(part, mol, W_ro_in, b_ro_in, g1);
    k_ro_hid<<<RH / 64, 256, 0, stream>>>(g1, W_ro_hid, b_ro_hid, g2);
    k_ro_hid<<<RH / 64, 256, 0, stream>>>(g2, W_ro_hid + RH * RH, b_ro_hid + RH, g3);
    k_out<<<1, 256, 0, stream>>>(g3, W_out, b_out, (float*)d_out);

    // ---- diagnostic probes (scratch-only; real output already written) ----
    p_depth<<<DBLOCKS, 256, 0, stream>>>(
        hb_a, hb_s, cnt, colidx, snei_a, sself_a, snei_s, sself_s,
        W_node, b_node, W_att, b_att);
    p_scan<<<N / 4, 256, 0, stream>>>((const float4*)A, cnt_s, colidx_s);
    p_in<<<N / 32, 256, 0, stream>>>(X, W_in, b_in, h0_s);
}

// Round 8
// 389.684 us; speedup vs baseline: 6.6708x; 6.6708x over previous
//
#include <hip/hip_runtime.h>
#include <hip/hip_bf16.h>
#include <math.h>

#define N 8192
#define F 133
#define FP 136
#define H 256
#define MF 200
#define RH 512
#define MAXDEG 128
#define DROWS 8
#define DBLOCKS (N / DROWS)   // 1024

typedef unsigned short bfu;

static __device__ __forceinline__ bfu f2bf(float f) {
    unsigned u = __builtin_bit_cast(unsigned, f);
    u = (u + 0x7fff + ((u >> 16) & 1)) >> 16;   // RNE, finite inputs
    return (bfu)u;
}
static __device__ __forceinline__ float bf2f(bfu b) {
    unsigned u = (unsigned)b << 16;
    return __builtin_bit_cast(float, u);
}

// ---------------- sparse index build: wave-per-row ballot compaction ----------------
__global__ __launch_bounds__(256) void k_scan(const float4* __restrict__ A4,
                                              int* __restrict__ cnt,
                                              int* __restrict__ colidx) {
    const int wave = threadIdx.x >> 6;
    const int lane = threadIdx.x & 63;
    const int row = blockIdx.x * 4 + wave;
    const float4* rowp = A4 + (size_t)row * (N / 4);
    const unsigned long long lmask = (1ull << lane) - 1ull;
    int base = 0;
    int* rowout = colidx + row * MAXDEG;
    for (int it = 0; it < N / 4 / 64; ++it) {
        float4 v = rowp[it * 64 + lane];
        int col0 = (it * 64 + lane) * 4;
        float vv[4] = {v.x, v.y, v.z, v.w};
#pragma unroll
        for (int c = 0; c < 4; ++c) {
            bool nz = (vv[c] != 0.0f);
            unsigned long long m = __ballot(nz);
            if (nz) {
                int pos = base + __popcll(m & lmask);
                if (pos < MAXDEG) rowout[pos] = col0 + c;
            }
            base += __popcll(m);
        }
    }
    if (lane == 0) cnt[row] = base < MAXDEG ? base : MAXDEG;
}

// ------- k_in: h0 = X@W_in + b_in (NO relu); scores(h0); hw0 = h0 @ W_node[0] -------
__global__ __launch_bounds__(256) void k_in(const float* __restrict__ X,
                                            const float* __restrict__ Win,
                                            const float* __restrict__ bin,
                                            const float* __restrict__ Watt,
                                            const float* __restrict__ Wn0,
                                            bfu* __restrict__ hwout,
                                            float* __restrict__ snei,
                                            float* __restrict__ sself) {
    __shared__ float xs[32][FP];     // X tile
    __shared__ float hs[32][260];    // h0 tile, row-major, pad 260
    const int t = threadIdx.x;
    const int w = t >> 6, l = t & 63;
    const int row0 = blockIdx.x * 32;
    for (int i = t; i < 32 * F; i += 256) {
        int r = i / F, f = i - r * F;
        xs[r][f] = X[(row0 + r) * F + f];
    }
    __syncthreads();
    {
        float acc[32];
#pragma unroll
        for (int r = 0; r < 32; ++r) acc[r] = 0.f;
        for (int f = 0; f < 132; f += 4) {
            float w0 = Win[(f + 0) * H + t];
            float w1 = Win[(f + 1) * H + t];
            float w2 = Win[(f + 2) * H + t];
            float w3 = Win[(f + 3) * H + t];
#pragma unroll
            for (int r = 0; r < 32; ++r) {
                float4 xv = *reinterpret_cast<const float4*>(&xs[r][f]);
                acc[r] = fmaf(xv.x, w0, acc[r]);
                acc[r] = fmaf(xv.y, w1, acc[r]);
                acc[r] = fmaf(xv.z, w2, acc[r]);
                acc[r] = fmaf(xv.w, w3, acc[r]);
            }
        }
        {
            float w0 = Win[132 * H + t];
#pragma unroll
            for (int r = 0; r < 32; ++r) acc[r] = fmaf(xs[r][132], w0, acc[r]);
        }
        float bb = bin[t];
#pragma unroll
        for (int r = 0; r < 32; ++r) hs[r][t] = acc[r] + bb;   // 2-way bank: free
    }
    __syncthreads();
    // scores: wave w owns rows 8w..8w+7; lane l holds feature quad 4l
    const int c0 = l << 2;
    {
        const float4 wanv = *reinterpret_cast<const float4*>(&Watt[c0]);
        const float4 wasv = *reinterpret_cast<const float4*>(&Watt[H + c0]);
#pragma unroll
        for (int i = 0; i < 8; ++i) {
            int r = w * 8 + i;
            float4 hv = *reinterpret_cast<const float4*>(&hs[r][c0]);
            float pn = hv.x * wanv.x + hv.y * wanv.y + hv.z * wanv.z + hv.w * wanv.w;
            float ps = hv.x * wasv.x + hv.y * wasv.y + hv.z * wasv.z + hv.w * wasv.w;
#pragma unroll
            for (int off = 32; off > 0; off >>= 1) {
                pn += __shfl_xor(pn, off);
                ps += __shfl_xor(ps, off);
            }
            if (l == 0) { snei[row0 + r] = pn; sself[row0 + r] = ps; }
        }
    }
    // GEMM0: hw0 tile = hs(32x256) @ Wn0(256x256); wave w rows 8w..8w+7, cols c0..c0+3
    {
        float acc2[8][4];
#pragma unroll
        for (int i = 0; i < 8; ++i)
#pragma unroll
            for (int j = 0; j < 4; ++j) acc2[i][j] = 0.f;
        for (int k4 = 0; k4 < 64; ++k4) {
            float4 av[8];
#pragma unroll
            for (int i = 0; i < 8; ++i)
                av[i] = *reinterpret_cast<const float4*>(&hs[w * 8 + i][k4 * 4]);
#pragma unroll
            for (int ki = 0; ki < 4; ++ki) {
                int kk = k4 * 4 + ki;
                float4 wv = *reinterpret_cast<const float4*>(&Wn0[kk * 256 + c0]);
                const float* ap;
#pragma unroll
                for (int i = 0; i < 8; ++i) {
                    ap = &av[i].x;
                    float a = ap[ki];
                    acc2[i][0] = fmaf(a, wv.x, acc2[i][0]);
                    acc2[i][1] = fmaf(a, wv.y, acc2[i][1]);
                    acc2[i][2] = fmaf(a, wv.z, acc2[i][2]);
                    acc2[i][3] = fmaf(a, wv.w, acc2[i][3]);
                }
            }
        }
#pragma unroll
        for (int i = 0; i < 8; ++i) {
            ushort4 o;
            o.x = f2bf(acc2[i][0]); o.y = f2bf(acc2[i][1]);
            o.z = f2bf(acc2[i][2]); o.w = f2bf(acc2[i][3]);
            *reinterpret_cast<ushort4*>(&hwout[(row0 + w * 8 + i) * H + c0]) = o;
        }
    }
}

// ------- k_gg: weights -> gather(hW) -> h_new=relu(+b) -> scores | colsum
//               -> GEMM h_new @ W_next -> hw_next    (8 rows/block, 1024 blocks)
template <bool LAST>
__global__ __launch_bounds__(256, 4) void k_gg(
    const bfu* __restrict__ hwin,
    const int* __restrict__ cnt, const int* __restrict__ colidx,
    const float* __restrict__ snei_in, const float* __restrict__ sself_in,
    float* __restrict__ snei_out, float* __restrict__ sself_out,
    const float* __restrict__ bn,      // b_node[d]
    const float* __restrict__ Wnext,   // W_node[d+1] (unused if LAST)
    const float* __restrict__ Watt, const float* __restrict__ b_att,
    bfu* __restrict__ hwout, float* __restrict__ part) {
    __shared__ float hs[DROWS][260];        // h_new tile
    __shared__ float wls[DROWS * 128];
    __shared__ int   jls[DROWS * 128];
    __shared__ float csred[4 * 256];
    __shared__ float sselfL[DROWS];
    __shared__ int   ncnt[DROWS];
    const int t = threadIdx.x;
    const int w = t >> 6, l = t & 63;
    const int c0 = l << 2;
    const int R0 = blockIdx.x * DROWS;

    if (t < DROWS) { ncnt[t] = cnt[R0 + t]; sselfL[t] = sself_in[R0 + t] + b_att[0]; }
    __syncthreads();
#pragma unroll
    for (int rep = 0; rep < 4; ++rep) {
        int idx = t + rep * 256;
        int r = idx >> 7, k = idx & 127;
        if (k < ncnt[r]) {
            int j = colidx[(R0 + r) * MAXDEG + k];
            jls[idx] = j;
            wls[idx] = 1.f / (1.f + __expf(-(sselfL[r] + snei_in[j])));
        }
    }
    __syncthreads();

    const float4 bv = *reinterpret_cast<const float4*>(&bn[c0]);
    float4 wanv, wasv;
    if (!LAST) {
        wanv = *reinterpret_cast<const float4*>(&Watt[c0]);
        wasv = *reinterpret_cast<const float4*>(&Watt[H + c0]);
    }
    float cs0 = 0.f, cs1 = 0.f, cs2 = 0.f, cs3 = 0.f;
    // gather: wave w owns rows 2w, 2w+1
#pragma unroll
    for (int rr = 0; rr < 2; ++rr) {
        const int r = 2 * w + rr;
        const int n = ncnt[r];
#define GSTEP(u, sx, sy, sz, sw)                                                  \
        { int ju = jls[r * 128 + k + u]; float wv = wls[r * 128 + k + u];         \
          ushort4 hv = *reinterpret_cast<const ushort4*>(&hwin[ju * 256 + c0]);   \
          sx = fmaf(wv, bf2f(hv.x), sx); sy = fmaf(wv, bf2f(hv.y), sy);           \
          sz = fmaf(wv, bf2f(hv.z), sz); sw = fmaf(wv, bf2f(hv.w), sw); }
        float x0=0,y0=0,z0=0,w0=0, x1=0,y1=0,z1=0,w1=0;
        float x2=0,y2=0,z2=0,w2=0, x3=0,y3=0,z3=0,w3=0;
        float x4=0,y4=0,z4=0,w4=0, x5=0,y5=0,z5=0,w5=0;
        float x6=0,y6=0,z6=0,w6=0, x7=0,y7=0,z7=0,w7=0;
        int k = 0;
        for (; k + 8 <= n; k += 8) {
            GSTEP(0,x0,y0,z0,w0) GSTEP(1,x1,y1,z1,w1)
            GSTEP(2,x2,y2,z2,w2) GSTEP(3,x3,y3,z3,w3)
            GSTEP(4,x4,y4,z4,w4) GSTEP(5,x5,y5,z5,w5)
            GSTEP(6,x6,y6,z6,w6) GSTEP(7,x7,y7,z7,w7)
        }
        for (; k < n; ++k) { GSTEP(0,x0,y0,z0,w0) }
#undef GSTEP
        float v0 = ((x0+x1)+(x2+x3)) + ((x4+x5)+(x6+x7)) + bv.x;
        float v1 = ((y0+y1)+(y2+y3)) + ((y4+y5)+(y6+y7)) + bv.y;
        float v2 = ((z0+z1)+(z2+z3)) + ((z4+z5)+(z6+z7)) + bv.z;
        float v3 = ((w0+w1)+(w2+w3)) + ((w4+w5)+(w6+w7)) + bv.w;
        v0 = v0 > 0.f ? v0 : 0.f;
        v1 = v1 > 0.f ? v1 : 0.f;
        v2 = v2 > 0.f ? v2 : 0.f;
        v3 = v3 > 0.f ? v3 : 0.f;
        float4 st; st.x = v0; st.y = v1; st.z = v2; st.w = v3;
        *reinterpret_cast<float4*>(&hs[r][c0]) = st;
        if (!LAST) {
            float pn = v0 * wanv.x + v1 * wanv.y + v2 * wanv.z + v3 * wanv.w;
            float ps = v0 * wasv.x + v1 * wasv.y + v2 * wasv.z + v3 * wasv.w;
#pragma unroll
            for (int off = 32; off > 0; off >>= 1) {
                pn += __shfl_xor(pn, off);
                ps += __shfl_xor(ps, off);
            }
            if (l == 0) { snei_out[R0 + r] = pn; sself_out[R0 + r] = ps; }
        } else {
            cs0 += v0; cs1 += v1; cs2 += v2; cs3 += v3;
        }
    }
    if (LAST) {
        csred[w * 256 + c0 + 0] = cs0;
        csred[w * 256 + c0 + 1] = cs1;
        csred[w * 256 + c0 + 2] = cs2;
        csred[w * 256 + c0 + 3] = cs3;
        __syncthreads();
        part[blockIdx.x * H + t] =
            (csred[t] + csred[256 + t]) + (csred[512 + t] + csred[768 + t]);
        return;
    }
    __syncthreads();
    // GEMM: hw_next tile = hs(8x256) @ Wnext; wave w rows {2w,2w+1}, cols c0
    {
        float acc[2][4];
#pragma unroll
        for (int i = 0; i < 2; ++i)
#pragma unroll
            for (int j = 0; j < 4; ++j) acc[i][j] = 0.f;
#pragma unroll 2
        for (int k4 = 0; k4 < 64; ++k4) {
            float4 a0 = *reinterpret_cast<const float4*>(&hs[2 * w + 0][k4 * 4]);
            float4 a1 = *reinterpret_cast<const float4*>(&hs[2 * w + 1][k4 * 4]);
            const float* a0p = &a0.x;
            const float* a1p = &a1.x;
#pragma unroll
            for (int ki = 0; ki < 4; ++ki) {
                int kk = k4 * 4 + ki;
                float4 wv = *reinterpret_cast<const float4*>(&Wnext[kk * 256 + c0]);
                float aa0 = a0p[ki], aa1 = a1p[ki];
                acc[0][0] = fmaf(aa0, wv.x, acc[0][0]);
                acc[0][1] = fmaf(aa0, wv.y, acc[0][1]);
                acc[0][2] = fmaf(aa0, wv.z, acc[0][2]);
                acc[0][3] = fmaf(aa0, wv.w, acc[0][3]);
                acc[1][0] = fmaf(aa1, wv.x, acc[1][0]);
                acc[1][1] = fmaf(aa1, wv.y, acc[1][1]);
                acc[1][2] = fmaf(aa1, wv.z, acc[1][2]);
                acc[1][3] = fmaf(aa1, wv.w, acc[1][3]);
            }
        }
#pragma unroll
        for (int i = 0; i < 2; ++i) {
            ushort4 o;
            o.x = f2bf(acc[i][0]); o.y = f2bf(acc[i][1]);
            o.z = f2bf(acc[i][2]); o.w = f2bf(acc[i][3]);
            *reinterpret_cast<ushort4*>(&hwout[(R0 + 2 * w + i) * H + c0]) = o;
        }
    }
}

// ---------------- readout layer 1: g=[colsum(1024 parts), mol] (K=456) ----------------
__global__ __launch_bounds__(256) void k_ro1(const float* __restrict__ part,
                                             const float* __restrict__ mol,
                                             const float* __restrict__ W,
                                             const float* __restrict__ b,
                                             float* __restrict__ out) {
    __shared__ float xin[H + MF];
    __shared__ float red[256];
    const int t = threadIdx.x;
    {
        float s0 = 0.f, s1 = 0.f, s2 = 0.f, s3 = 0.f;
        for (int bb = 0; bb < DBLOCKS; bb += 4) {
            s0 += part[(bb + 0) * H + t];
            s1 += part[(bb + 1) * H + t];
            s2 += part[(bb + 2) * H + t];
            s3 += part[(bb + 3) * H + t];
        }
        xin[t] = (s0 + s1) + (s2 + s3);
    }
    if (t < MF) xin[H + t] = mol[t];
    __syncthreads();
    const int o = blockIdx.x * 64 + (t & 63);
    const int kg = t >> 6;
    float acc = 0.f;
    for (int k = kg; k < H + MF; k += 4) acc = fmaf(xin[k], W[k * RH + o], acc);
    red[t] = acc;
    __syncthreads();
    if (t < 64) {
        float v = red[t] + red[t + 64] + red[t + 128] + red[t + 192] + b[o];
        out[o] = v > 0.f ? v : 0.f;
    }
}

// ---------------- readout hidden layer (K=512) ----------------
__global__ __launch_bounds__(256) void k_ro_hid(const float* __restrict__ g,
                                                const float* __restrict__ W,
                                                const float* __restrict__ b,
                                                float* __restrict__ out) {
    __shared__ float xin[RH];
    __shared__ float red[256];
    const int t = threadIdx.x;
    xin[t] = g[t];
    xin[t + 256] = g[t + 256];
    __syncthreads();
    const int o = blockIdx.x * 64 + (t & 63);
    const int kg = t >> 6;
    float acc = 0.f;
    for (int k = kg; k < RH; k += 4) acc = fmaf(xin[k], W[k * RH + o], acc);
    red[t] = acc;
    __syncthreads();
    if (t < 64) {
        float v = red[t] + red[t + 64] + red[t + 128] + red[t + 192] + b[o];
        out[o] = v > 0.f ? v : 0.f;
    }
}

// ---------------- final dot ----------------
__global__ __launch_bounds__(256) void k_out(const float* __restrict__ g,
                                             const float* __restrict__ W,
                                             const float* __restrict__ bo,
                                             float* __restrict__ out) {
    __shared__ float red[256];
    int t = threadIdx.x;
    red[t] = g[t] * W[t] + g[t + 256] * W[t + 256];
    __syncthreads();
    for (int s = 128; s > 0; s >>= 1) {
        if (t < s) red[t] += red[t + s];
        __syncthreads();
    }
    if (t == 0) out[0] = red[0] + bo[0];
}

extern "C" void kernel_launch(void* const* d_in, const int* in_sizes, int n_in,
                              void* d_out, int out_size, void* d_ws, size_t ws_size,
                              hipStream_t stream) {
    const float* A        = (const float*)d_in[0];
    const float* X        = (const float*)d_in[1];
    const float* mol      = (const float*)d_in[2];
    const float* W_in     = (const float*)d_in[3];
    const float* b_in     = (const float*)d_in[4];
    const float* W_att    = (const float*)d_in[5];
    const float* b_att    = (const float*)d_in[6];
    const float* W_node   = (const float*)d_in[7];
    const float* b_node   = (const float*)d_in[8];
    const float* W_ro_in  = (const float*)d_in[9];
    const float* b_ro_in  = (const float*)d_in[10];
    const float* W_ro_hid = (const float*)d_in[11];
    const float* b_ro_hid = (const float*)d_in[12];
    const float* W_out    = (const float*)d_in[13];
    const float* b_out    = (const float*)d_in[14];

    char* ws = (char*)d_ws;
    bfu*   hw_a   = (bfu*)  (ws);                        // 4 MB  (h_d @ W_d, bf16)
    bfu*   hw_b   = (bfu*)  (ws + 4194304);              // 4 MB
    int*   colidx = (int*)  (ws + 8388608);              // 4 MB
    int*   cnt    = (int*)  (ws + 12582912);             // 32 KB
    float* snei_a = (float*)(ws + 12615680);             // 32 KB
    float* sself_a= (float*)(ws + 12648448);             // 32 KB
    float* snei_b = (float*)(ws + 12681216);             // 32 KB
    float* sself_b= (float*)(ws + 12713984);             // 32 KB
    float* part   = (float*)(ws + 12746752);             // 1 MB (1024 x 256)
    float* g1     = (float*)(ws + 13795328);             // 2 KB
    float* g2     = (float*)(ws + 13797376);             // 2 KB
    float* g3     = (float*)(ws + 13799424);             // 2 KB

    k_scan<<<N / 4, 256, 0, stream>>>((const float4*)A, cnt, colidx);
    // h0 + scores0 + hw0 = h0 @ W_node[0]
    k_in<<<N / 32, 256, 0, stream>>>(X, W_in, b_in, W_att, W_node, hw_a,
                                     snei_a, sself_a);
    // depth 0: gather hw_a -> h1 (b_node[0]) -> scores -> GEMM @ W_node[1] -> hw_b
    k_gg<false><<<DBLOCKS, 256, 0, stream>>>(
        hw_a, cnt, colidx, snei_a, sself_a, snei_b, sself_b,
        b_node + 0 * H, W_node + 1 * H * H, W_att, b_att, hw_b, nullptr);
    // depth 1: hw_b -> h2 (b_node[1]) -> scores -> GEMM @ W_node[2] -> hw_a
    k_gg<false><<<DBLOCKS, 256, 0, stream>>>(
        hw_b, cnt, colidx, snei_b, sself_b, snei_a, sself_a,
        b_node + 1 * H, W_node + 2 * H * H, W_att, b_att, hw_a, nullptr);
    // depth 2 (last): hw_a -> h3 (b_node[2]) -> colsum partials
    k_gg<true><<<DBLOCKS, 256, 0, stream>>>(
        hw_a, cnt, colidx, snei_a, sself_a, nullptr, nullptr,
        b_node + 2 * H, nullptr, W_att, b_att, nullptr, part);

    k_ro1<<<RH / 64, 256, 0, stream>>>(part, mol, W_ro_in, b_ro_in, g1);
    k_ro_hid<<<RH / 64, 256, 0, stream>>>(g1, W_ro_hid, b_ro_hid, g2);
    k_ro_hid<<<RH / 64, 256, 0, stream>>>(g2, W_ro_hid + RH * RH, b_ro_hid + RH, g3);
    k_out<<<1, 256, 0, stream>>>(g3, W_out, b_out, (float*)d_out);
}

// Round 9
// 367.948 us; speedup vs baseline: 7.0649x; 1.0591x over previous
//
#include <hip/hip_runtime.h>
#include <hip/hip_bf16.h>
#include <math.h>

#define N 8192
#define F 133
#define FP 136
#define H 256
#define MF 200
#define RH 512
#define MAXDEG 128

typedef unsigned short bfu;

static __device__ __forceinline__ bfu f2bf(float f) {
    unsigned u = __builtin_bit_cast(unsigned, f);
    u = (u + 0x7fff + ((u >> 16) & 1)) >> 16;   // RNE, finite inputs
    return (bfu)u;
}
static __device__ __forceinline__ float bf2f(bfu b) {
    unsigned u = (unsigned)b << 16;
    return __builtin_bit_cast(float, u);
}
static __device__ __forceinline__ float bflo(unsigned u) {
    return __builtin_bit_cast(float, u << 16);
}
static __device__ __forceinline__ float bfhi(unsigned u) {
    return __builtin_bit_cast(float, u & 0xffff0000u);
}

// ============ k_front: scan(2048) | h0+scores0(256) | W_ro->bf16T(16) ============
__global__ __launch_bounds__(256) void k_front(
    const float4* __restrict__ A4, int* __restrict__ cnt, int* __restrict__ colidx,
    const float* __restrict__ X, const float* __restrict__ Win,
    const float* __restrict__ bin, const float* __restrict__ Watt,
    const float* __restrict__ Wro1, const float* __restrict__ Wroh,
    bfu* __restrict__ hb, float* __restrict__ snei, float* __restrict__ sself,
    bfu* __restrict__ Wt) {
    const int t = threadIdx.x;
    const int b = blockIdx.x;
    if (b < 2048) {
        // ---- A-scan: wave-per-row ballot compaction ----
        const int wave = t >> 6;
        const int lane = t & 63;
        const int row = b * 4 + wave;
        const float4* rowp = A4 + (size_t)row * (N / 4);
        const unsigned long long lmask = (1ull << lane) - 1ull;
        int base = 0;
        int* rowout = colidx + row * MAXDEG;
        for (int it = 0; it < N / 4 / 64; ++it) {
            float4 v = rowp[it * 64 + lane];
            int col0 = (it * 64 + lane) * 4;
            float vv[4] = {v.x, v.y, v.z, v.w};
#pragma unroll
            for (int c = 0; c < 4; ++c) {
                bool nz = (vv[c] != 0.0f);
                unsigned long long m = __ballot(nz);
                if (nz) {
                    int pos = base + __popcll(m & lmask);
                    if (pos < MAXDEG) rowout[pos] = col0 + c;
                }
                base += __popcll(m);
            }
        }
        if (lane == 0) cnt[row] = base < MAXDEG ? base : MAXDEG;
        return;
    }
    if (b >= 2304) {
        // ---- convert readout weights to bf16, TRANSPOSED [o][k], K padded 512 ----
        const int gtid = (b - 2304) * 256 + t;   // 0..4095
        const int row = gtid >> 3;               // output 0..511
        const int sub = gtid & 7;
#pragma unroll 1
        for (int m = 0; m < 3; ++m) {
            bfu* dst = Wt + m * 512 * 512;
#pragma unroll 8
            for (int i = 0; i < 64; ++i) {
                int k = sub + i * 8;
                float v;
                if (m == 0) v = (k < H + MF) ? Wro1[k * RH + row] : 0.f;
                else        v = Wroh[(m - 1) * RH * RH + k * RH + row];
                dst[row * 512 + k] = f2bf(v);
            }
        }
        return;
    }
    // ---- h0 = X @ W_in + b_in -> bf16, + scores of h0 ----
    __shared__ float xs[32][FP];
    __shared__ float sredN[32][4];
    __shared__ float sredS[32][4];
    const int row0 = (b - 2048) * 32;
    for (int i = t; i < 32 * F; i += 256) {
        int r = i / F, f = i - r * F;
        xs[r][f] = X[(row0 + r) * F + f];
    }
    __syncthreads();
    float acc[32];
#pragma unroll
    for (int r = 0; r < 32; ++r) acc[r] = 0.f;
    for (int f = 0; f < 132; f += 4) {
        float w0 = Win[(f + 0) * H + t];
        float w1 = Win[(f + 1) * H + t];
        float w2 = Win[(f + 2) * H + t];
        float w3 = Win[(f + 3) * H + t];
#pragma unroll
        for (int r = 0; r < 32; ++r) {
            float4 xv = *reinterpret_cast<const float4*>(&xs[r][f]);
            acc[r] = fmaf(xv.x, w0, acc[r]);
            acc[r] = fmaf(xv.y, w1, acc[r]);
            acc[r] = fmaf(xv.z, w2, acc[r]);
            acc[r] = fmaf(xv.w, w3, acc[r]);
        }
    }
    {
        float w0 = Win[132 * H + t];
#pragma unroll
        for (int r = 0; r < 32; ++r) acc[r] = fmaf(xs[r][132], w0, acc[r]);
    }
    const float bb = bin[t];
    const float wan = Watt[t];
    const float was = Watt[H + t];
    const int wv = t >> 6, ln = t & 63;
#pragma unroll
    for (int r = 0; r < 32; ++r) {
        float v = acc[r] + bb;
        hb[(row0 + r) * H + t] = f2bf(v);
        float pn = v * wan;
        float ps = v * was;
        for (int off = 32; off > 0; off >>= 1) {
            pn += __shfl_down(pn, off);
            ps += __shfl_down(ps, off);
        }
        if (ln == 0) { sredN[r][wv] = pn; sredS[r][wv] = ps; }
    }
    __syncthreads();
    if (t < 32)
        snei[row0 + t] = (sredN[t][0] + sredN[t][1]) + (sredN[t][2] + sredN[t][3]);
    else if (t < 64) {
        int r = t - 32;
        sself[row0 + r] = (sredS[r][0] + sredS[r][1]) + (sredS[r][2] + sredS[r][3]);
    }
}

// ============ k_agg: gather h (bf16) -> hg (fp32); zero next score bufs ============
__global__ __launch_bounds__(256, 4) void k_agg(
    const bfu* __restrict__ hb, float* __restrict__ hg,
    const int* __restrict__ cnt, const int* __restrict__ colidx,
    const float* __restrict__ snei_in, const float* __restrict__ sself_in,
    const float* __restrict__ b_att,
    float* __restrict__ zn, float* __restrict__ zs) {
    __shared__ float wls[512];
    __shared__ int   jls[512];
    __shared__ float sselfL[4];
    __shared__ int   ncnt[4];
    const int t = threadIdx.x;
    const int w = t >> 6, l = t & 63;
    const int c0 = l << 2;
    const int R0 = blockIdx.x * 4;
    if (blockIdx.x < 64) {   // zero the score buffers the next k_node atomic-adds
        if (t < 128) zn[blockIdx.x * 128 + t] = 0.f;
        else         zs[blockIdx.x * 128 + (t - 128)] = 0.f;
    }
    if (t < 4) { ncnt[t] = cnt[R0 + t]; sselfL[t] = sself_in[R0 + t] + b_att[0]; }
    __syncthreads();
#pragma unroll
    for (int rep = 0; rep < 2; ++rep) {
        int idx = t + rep * 256;
        int r = idx >> 7, k = idx & 127;
        if (k < ncnt[r]) {
            int j = colidx[(R0 + r) * MAXDEG + k];
            jls[idx] = j;
            wls[idx] = 1.f / (1.f + __expf(-(sselfL[r] + snei_in[j])));
        }
    }
    __syncthreads();
    const int n = ncnt[w];
#define GSTEP(u, sx, sy, sz, sw)                                                  \
    { int ju = jls[w * 128 + k + u]; float wv = wls[w * 128 + k + u];             \
      ushort4 hv = *reinterpret_cast<const ushort4*>(&hb[ju * 256 + c0]);         \
      sx = fmaf(wv, bf2f(hv.x), sx); sy = fmaf(wv, bf2f(hv.y), sy);               \
      sz = fmaf(wv, bf2f(hv.z), sz); sw = fmaf(wv, bf2f(hv.w), sw); }
    float x0=0,y0=0,z0=0,w0=0, x1=0,y1=0,z1=0,w1=0;
    float x2=0,y2=0,z2=0,w2=0, x3=0,y3=0,z3=0,w3=0;
    float x4=0,y4=0,z4=0,w4=0, x5=0,y5=0,z5=0,w5=0;
    float x6=0,y6=0,z6=0,w6=0, x7=0,y7=0,z7=0,w7=0;
    int k = 0;
    for (; k + 8 <= n; k += 8) {
        GSTEP(0,x0,y0,z0,w0) GSTEP(1,x1,y1,z1,w1)
        GSTEP(2,x2,y2,z2,w2) GSTEP(3,x3,y3,z3,w3)
        GSTEP(4,x4,y4,z4,w4) GSTEP(5,x5,y5,z5,w5)
        GSTEP(6,x6,y6,z6,w6) GSTEP(7,x7,y7,z7,w7)
    }
    for (; k < n; ++k) { GSTEP(0,x0,y0,z0,w0) }
#undef GSTEP
    float4 st;
    st.x = ((x0+x1)+(x2+x3)) + ((x4+x5)+(x6+x7));
    st.y = ((y0+y1)+(y2+y3)) + ((y4+y5)+(y6+y7));
    st.z = ((z0+z1)+(z2+z3)) + ((z4+z5)+(z6+z7));
    st.w = ((w0+w1)+(w2+w3)) + ((w4+w5)+(w6+w7));
    *reinterpret_cast<float4*>(&hg[(size_t)(R0 + w) * 256 + c0]) = st;
}

// ===== k_node: h_next = relu(hg @ W + b); epilogue: atomic scores | colsum part =====
#define BM 64
#define BN 64
#define BK 32
template <bool LAST>
__global__ __launch_bounds__(256) void k_node(
    const float* __restrict__ hin, bfu* __restrict__ hout,
    const float* __restrict__ W, const float* __restrict__ b,
    const float* __restrict__ Watt,
    float* __restrict__ snei_out, float* __restrict__ sself_out,
    float* __restrict__ part) {
    __shared__ float As[BK][BM];
    __shared__ float Ws[BK][BN];
    __shared__ float sredA[16][64];
    __shared__ float sredB[16][64];
    const int tid = threadIdx.x;
    const int tx = tid & 15;
    const int ty = tid >> 4;
    const int m0 = tx * 4, n0 = ty * 4;
    const int brow = blockIdx.x * BM;
    const int bcol = blockIdx.y * BN;
    const int sm = tid & 63;
    const int sk4 = tid >> 6;
    float acc[4][4] = {{0.f}};
    for (int k0 = 0; k0 < H; k0 += BK) {
#pragma unroll
        for (int half = 0; half < 2; ++half) {
            int kk = 4 * sk4 + 16 * half;
            float4 a = *reinterpret_cast<const float4*>(&hin[(brow + sm) * H + k0 + kk]);
            As[kk + 0][sm] = a.x;
            As[kk + 1][sm] = a.y;
            As[kk + 2][sm] = a.z;
            As[kk + 3][sm] = a.w;
        }
#pragma unroll
        for (int half = 0; half < 2; ++half) {
            int idx = tid + 256 * half;
            int kr = idx >> 4;
            int nq = idx & 15;
            float4 w = *reinterpret_cast<const float4*>(&W[(k0 + kr) * H + bcol + nq * 4]);
            *reinterpret_cast<float4*>(&Ws[kr][nq * 4]) = w;
        }
        __syncthreads();
#pragma unroll
        for (int k = 0; k < BK; ++k) {
            float4 av = *reinterpret_cast<const float4*>(&As[k][m0]);
            float4 wv = *reinterpret_cast<const float4*>(&Ws[k][n0]);
            float a[4] = {av.x, av.y, av.z, av.w};
            float w[4] = {wv.x, wv.y, wv.z, wv.w};
#pragma unroll
            for (int i = 0; i < 4; ++i)
#pragma unroll
                for (int j = 0; j < 4; ++j) acc[i][j] = fmaf(a[i], w[j], acc[i][j]);
        }
        __syncthreads();
    }
    // bias + relu (+ store bf16 unless LAST)
    float v[4][4];
    float4 wanv, wasv;
    if (!LAST) {
        wanv = *reinterpret_cast<const float4*>(&Watt[bcol + n0]);
        wasv = *reinterpret_cast<const float4*>(&Watt[H + bcol + n0]);
    }
#pragma unroll
    for (int i = 0; i < 4; ++i) {
#pragma unroll
        for (int j = 0; j < 4; ++j) {
            float x = acc[i][j] + b[bcol + n0 + j];
            v[i][j] = x > 0.f ? x : 0.f;
        }
        if (!LAST) {
            ushort4 o;
            o.x = f2bf(v[i][0]); o.y = f2bf(v[i][1]);
            o.z = f2bf(v[i][2]); o.w = f2bf(v[i][3]);
            *reinterpret_cast<ushort4*>(&hout[(brow + m0 + i) * H + bcol + n0]) = o;
        }
    }
    if (!LAST) {
        // partial attention scores for these 64 cols -> atomicAdd per row
#pragma unroll
        for (int i = 0; i < 4; ++i) {
            float pn = v[i][0]*wanv.x + v[i][1]*wanv.y + v[i][2]*wanv.z + v[i][3]*wanv.w;
            float ps = v[i][0]*wasv.x + v[i][1]*wasv.y + v[i][2]*wasv.z + v[i][3]*wasv.w;
            sredA[ty][m0 + i] = pn;   // overwritten per i? no: index depends on i
            sredB[ty][m0 + i] = ps;
        }
        __syncthreads();
        if (tid < 64) {
            float s = 0.f;
#pragma unroll
            for (int q = 0; q < 16; ++q) s += sredA[q][tid];
            atomicAdd(&snei_out[brow + tid], s);
        } else if (tid < 128) {
            int r = tid - 64;
            float s = 0.f;
#pragma unroll
            for (int q = 0; q < 16; ++q) s += sredB[q][r];
            atomicAdd(&sself_out[brow + r], s);
        }
    } else {
        // colsum partial over this block's 64 rows, 64 cols
        float cp[4];
#pragma unroll
        for (int j = 0; j < 4; ++j) cp[j] = (v[0][j] + v[1][j]) + (v[2][j] + v[3][j]);
#pragma unroll
        for (int j = 0; j < 4; ++j) sredA[tx][n0 + j] = cp[j];
        __syncthreads();
        if (tid < 64) {
            float s = 0.f;
#pragma unroll
            for (int q = 0; q < 16; ++q) s += sredA[q][tid];
            part[blockIdx.x * 256 + bcol + tid] = s;
        }
    }
}

// ============ k_ro: entire readout in one 512-thread block ============
__global__ __launch_bounds__(512) void k_ro(
    const float* __restrict__ part, const float* __restrict__ mol,
    const bfu* __restrict__ Wt, const float* __restrict__ b1,
    const float* __restrict__ bh, const float* __restrict__ Wo,
    const float* __restrict__ bo, float* __restrict__ out) {
    __shared__ float xa[512], xb[512], red[512];
    const int t = threadIdx.x;
    {
        const int col = t & 255;
        const int r0 = (t < 256) ? 0 : 64;
        float s = 0.f;
        for (int r = 0; r < 64; ++r) s += part[(r0 + r) * 256 + col];
        red[t] = s;
    }
    __syncthreads();
    if (t < 256) xa[t] = red[t] + red[t + 256];
    else { int i = t - 256; xa[256 + i] = (i < MF) ? mol[i] : 0.f; }
    __syncthreads();
    float* xin = xa;
    float* xo = xb;
    const int w = t >> 6, l = t & 63;
#pragma unroll 1
    for (int L = 0; L < 3; ++L) {
        const bfu* Wl = Wt + L * 512 * 512;
        const float* bl = (L == 0) ? b1 : (bh + (L - 1) * RH);
#pragma unroll 4
        for (int i = 0; i < 64; ++i) {
            const int o = w * 64 + i;
            uint4 u = *reinterpret_cast<const uint4*>(&Wl[o * 512 + l * 8]);
            float4 x0 = *reinterpret_cast<const float4*>(&xin[l * 8]);
            float4 x1 = *reinterpret_cast<const float4*>(&xin[l * 8 + 4]);
            float d = x0.x * bflo(u.x) + x0.y * bfhi(u.x)
                    + x0.z * bflo(u.y) + x0.w * bfhi(u.y)
                    + x1.x * bflo(u.z) + x1.y * bfhi(u.z)
                    + x1.z * bflo(u.w) + x1.w * bfhi(u.w);
            for (int off = 32; off > 0; off >>= 1) d += __shfl_down(d, off);
            if (l == 0) {
                float vv = d + bl[o];
                xo[o] = vv > 0.f ? vv : 0.f;
            }
        }
        __syncthreads();
        float* tmp = xin; xin = xo; xo = tmp;
    }
    red[t] = xin[t] * Wo[t];
    __syncthreads();
    for (int s = 256; s > 0; s >>= 1) {
        if (t < s) red[t] += red[t + s];
        __syncthreads();
    }
    if (t == 0) out[0] = red[0] + bo[0];
}

extern "C" void kernel_launch(void* const* d_in, const int* in_sizes, int n_in,
                              void* d_out, int out_size, void* d_ws, size_t ws_size,
                              hipStream_t stream) {
    const float* A        = (const float*)d_in[0];
    const float* X        = (const float*)d_in[1];
    const float* mol      = (const float*)d_in[2];
    const float* W_in     = (const float*)d_in[3];
    const float* b_in     = (const float*)d_in[4];
    const float* W_att    = (const float*)d_in[5];
    const float* b_att    = (const float*)d_in[6];
    const float* W_node   = (const float*)d_in[7];
    const float* b_node   = (const float*)d_in[8];
    const float* W_ro_in  = (const float*)d_in[9];
    const float* b_ro_in  = (const float*)d_in[10];
    const float* W_ro_hid = (const float*)d_in[11];
    const float* b_ro_hid = (const float*)d_in[12];
    const float* W_out    = (const float*)d_in[13];
    const float* b_out    = (const float*)d_in[14];

    char* ws = (char*)d_ws;
    bfu*   hb     = (bfu*)  (ws);                        // 4 MB bf16 h
    float* hg     = (float*)(ws + 4194304);              // 8 MB fp32 aggregate
    int*   colidx = (int*)  (ws + 12582912);             // 4 MB
    int*   cnt    = (int*)  (ws + 16777216);             // 32 KB
    float* s0n    = (float*)(ws + 16809984);             // 32 KB
    float* s0s    = (float*)(ws + 16842752);             // 32 KB
    float* s1n    = (float*)(ws + 16875520);             // 32 KB
    float* s1s    = (float*)(ws + 16908288);             // 32 KB
    float* part   = (float*)(ws + 16941056);             // 128 KB (128x256)
    bfu*   Wt     = (bfu*)  (ws + 17072128);             // 1.5 MB bf16T readout W

    // front: scan (blocks 0..2047) | h0+scores0 (2048..2303) | W_ro convert (2304..2319)
    k_front<<<2320, 256, 0, stream>>>((const float4*)A, cnt, colidx,
                                      X, W_in, b_in, W_att, W_ro_in, W_ro_hid,
                                      hb, s0n, s0s, Wt);
    // depth 0
    k_agg<<<N / 4, 256, 0, stream>>>(hb, hg, cnt, colidx, s0n, s0s, b_att, s1n, s1s);
    k_node<false><<<dim3(N / BM, H / BN), 256, 0, stream>>>(
        hg, hb, W_node + 0 * H * H, b_node + 0 * H, W_att, s1n, s1s, nullptr);
    // depth 1
    k_agg<<<N / 4, 256, 0, stream>>>(hb, hg, cnt, colidx, s1n, s1s, b_att, s0n, s0s);
    k_node<false><<<dim3(N / BM, H / BN), 256, 0, stream>>>(
        hg, hb, W_node + 1 * H * H, b_node + 1 * H, W_att, s0n, s0s, nullptr);
    // depth 2 (last): colsum partials, no h store
    k_agg<<<N / 4, 256, 0, stream>>>(hb, hg, cnt, colidx, s0n, s0s, b_att, s1n, s1s);
    k_node<true><<<dim3(N / BM, H / BN), 256, 0, stream>>>(
        hg, nullptr, W_node + 2 * H * H, b_node + 2 * H, W_att, nullptr, nullptr, part);
    // fused readout
    k_ro<<<1, 512, 0, stream>>>(part, mol, Wt, b_ro_in, b_ro_hid, W_out, b_out,
                                (float*)d_out);
}

// Round 10
// 354.076 us; speedup vs baseline: 7.3416x; 1.0392x over previous
//
#include <hip/hip_runtime.h>
#include <hip/hip_bf16.h>
#include <math.h>

#define N 8192
#define F 133
#define FP 136
#define H 256
#define MF 200
#define RH 512
#define MAXDEG 128

typedef unsigned short bfu;

static __device__ __forceinline__ bfu f2bf(float f) {
    unsigned u = __builtin_bit_cast(unsigned, f);
    u = (u + 0x7fff + ((u >> 16) & 1)) >> 16;   // RNE, finite inputs
    return (bfu)u;
}
static __device__ __forceinline__ float bf2f(bfu b) {
    unsigned u = (unsigned)b << 16;
    return __builtin_bit_cast(float, u);
}
static __device__ __forceinline__ float bflo(unsigned u) {
    return __builtin_bit_cast(float, u << 16);
}
static __device__ __forceinline__ float bfhi(unsigned u) {
    return __builtin_bit_cast(float, u & 0xffff0000u);
}

// ==== k_front: h0+scores0 (blocks 0..255) | W_ro->bf16T (256..271) | A-scan (272..2319)
// Scan uses LDS-atomic slot assignment (order-free) + 4-deep batched loads: no
// ballot serial chain, loads pipeline freely.
__global__ __launch_bounds__(256) void k_front(
    const float4* __restrict__ A4, int* __restrict__ cnt, int* __restrict__ colidx,
    const float* __restrict__ X, const float* __restrict__ Win,
    const float* __restrict__ bin, const float* __restrict__ Watt,
    const float* __restrict__ Wro1, const float* __restrict__ Wroh,
    bfu* __restrict__ hb, float* __restrict__ snei, float* __restrict__ sself,
    bfu* __restrict__ Wt) {
    const int t = threadIdx.x;
    const int b = blockIdx.x;
    if (b >= 272) {
        // ---------------- A-scan ----------------
        __shared__ int scnt[4];
        const int wave = t >> 6;
        const int lane = t & 63;
        const int row = (b - 272) * 4 + wave;
        const float4* rowp = A4 + (size_t)row * (N / 4);
        if (t < 4) scnt[t] = 0;
        __syncthreads();
        int* rowout = colidx + row * MAXDEG;
#pragma unroll 1
        for (int c = 0; c < 8; ++c) {
            float4 v[4];
#pragma unroll
            for (int u = 0; u < 4; ++u) v[u] = rowp[(c * 4 + u) * 64 + lane];
#pragma unroll
            for (int u = 0; u < 4; ++u) {
                const int col0 = ((c * 4 + u) * 64 + lane) * 4;
                const float* vp = &v[u].x;
#pragma unroll
                for (int q = 0; q < 4; ++q) {
                    if (vp[q] != 0.0f) {
                        int pos = atomicAdd(&scnt[wave], 1);
                        if (pos < MAXDEG) rowout[pos] = col0 + q;
                    }
                }
            }
        }
        __syncthreads();
        if (t < 4) {
            int n = scnt[t];
            cnt[(b - 272) * 4 + t] = n < MAXDEG ? n : MAXDEG;
        }
        return;
    }
    if (b >= 256) {
        // ---- convert readout weights to bf16, TRANSPOSED [o][k], K padded 512 ----
        const int gtid = (b - 256) * 256 + t;    // 0..4095
        const int row = gtid >> 3;               // output 0..511
        const int sub = gtid & 7;
#pragma unroll 1
        for (int m = 0; m < 3; ++m) {
            bfu* dst = Wt + m * 512 * 512;
#pragma unroll 8
            for (int i = 0; i < 64; ++i) {
                int k = sub + i * 8;
                float v;
                if (m == 0) v = (k < H + MF) ? Wro1[k * RH + row] : 0.f;
                else        v = Wroh[(m - 1) * RH * RH + k * RH + row];
                dst[row * 512 + k] = f2bf(v);
            }
        }
        return;
    }
    // ---------------- h0 = X @ W_in + b_in -> bf16, + scores of h0 ----------------
    __shared__ float xs[32][FP];
    __shared__ float sredN[32][4];
    __shared__ float sredS[32][4];
    const int row0 = b * 32;
    for (int i = t; i < 32 * F; i += 256) {
        int r = i / F, f = i - r * F;
        xs[r][f] = X[(row0 + r) * F + f];
    }
    __syncthreads();
    float acc[32];
#pragma unroll
    for (int r = 0; r < 32; ++r) acc[r] = 0.f;
    for (int f = 0; f < 132; f += 4) {
        float w0 = Win[(f + 0) * H + t];
        float w1 = Win[(f + 1) * H + t];
        float w2 = Win[(f + 2) * H + t];
        float w3 = Win[(f + 3) * H + t];
#pragma unroll
        for (int r = 0; r < 32; ++r) {
            float4 xv = *reinterpret_cast<const float4*>(&xs[r][f]);
            acc[r] = fmaf(xv.x, w0, acc[r]);
            acc[r] = fmaf(xv.y, w1, acc[r]);
            acc[r] = fmaf(xv.z, w2, acc[r]);
            acc[r] = fmaf(xv.w, w3, acc[r]);
        }
    }
    {
        float w0 = Win[132 * H + t];
#pragma unroll
        for (int r = 0; r < 32; ++r) acc[r] = fmaf(xs[r][132], w0, acc[r]);
    }
    const float bb = bin[t];
    const float wan = Watt[t];
    const float was = Watt[H + t];
    const int wv = t >> 6, ln = t & 63;
#pragma unroll
    for (int r = 0; r < 32; ++r) {
        float v = acc[r] + bb;
        hb[(row0 + r) * H + t] = f2bf(v);
        float pn = v * wan;
        float ps = v * was;
        for (int off = 32; off > 0; off >>= 1) {
            pn += __shfl_down(pn, off);
            ps += __shfl_down(ps, off);
        }
        if (ln == 0) { sredN[r][wv] = pn; sredS[r][wv] = ps; }
    }
    __syncthreads();
    if (t < 32)
        snei[row0 + t] = (sredN[t][0] + sredN[t][1]) + (sredN[t][2] + sredN[t][3]);
    else if (t < 64) {
        int r = t - 32;
        sself[row0 + r] = (sredS[r][0] + sredS[r][1]) + (sredS[r][2] + sredS[r][3]);
    }
}

// ============ k_agg: gather h (bf16) -> hg (fp32); zero next score bufs ============
__global__ __launch_bounds__(256, 4) void k_agg(
    const bfu* __restrict__ hb, float* __restrict__ hg,
    const int* __restrict__ cnt, const int* __restrict__ colidx,
    const float* __restrict__ snei_in, const float* __restrict__ sself_in,
    const float* __restrict__ b_att,
    float* __restrict__ zn, float* __restrict__ zs) {
    __shared__ float wls[512];
    __shared__ int   jls[512];
    __shared__ float sselfL[4];
    __shared__ int   ncnt[4];
    const int t = threadIdx.x;
    const int w = t >> 6, l = t & 63;
    const int c0 = l << 2;
    const int R0 = blockIdx.x * 4;
    if (blockIdx.x < 64) {   // zero the score buffers the next k_node atomic-adds
        if (t < 128) zn[blockIdx.x * 128 + t] = 0.f;
        else         zs[blockIdx.x * 128 + (t - 128)] = 0.f;
    }
    if (t < 4) { ncnt[t] = cnt[R0 + t]; sselfL[t] = sself_in[R0 + t] + b_att[0]; }
    __syncthreads();
#pragma unroll
    for (int rep = 0; rep < 2; ++rep) {
        int idx = t + rep * 256;
        int r = idx >> 7, k = idx & 127;
        if (k < ncnt[r]) {
            int j = colidx[(R0 + r) * MAXDEG + k];
            jls[idx] = j;
            wls[idx] = 1.f / (1.f + __expf(-(sselfL[r] + snei_in[j])));
        }
    }
    __syncthreads();
    const int n = ncnt[w];
#define GSTEP(u, sx, sy, sz, sw)                                                  \
    { int ju = jls[w * 128 + k + u]; float wv = wls[w * 128 + k + u];             \
      ushort4 hv = *reinterpret_cast<const ushort4*>(&hb[ju * 256 + c0]);         \
      sx = fmaf(wv, bf2f(hv.x), sx); sy = fmaf(wv, bf2f(hv.y), sy);               \
      sz = fmaf(wv, bf2f(hv.z), sz); sw = fmaf(wv, bf2f(hv.w), sw); }
    float x0=0,y0=0,z0=0,w0=0, x1=0,y1=0,z1=0,w1=0;
    float x2=0,y2=0,z2=0,w2=0, x3=0,y3=0,z3=0,w3=0;
    float x4=0,y4=0,z4=0,w4=0, x5=0,y5=0,z5=0,w5=0;
    float x6=0,y6=0,z6=0,w6=0, x7=0,y7=0,z7=0,w7=0;
    int k = 0;
    for (; k + 8 <= n; k += 8) {
        GSTEP(0,x0,y0,z0,w0) GSTEP(1,x1,y1,z1,w1)
        GSTEP(2,x2,y2,z2,w2) GSTEP(3,x3,y3,z3,w3)
        GSTEP(4,x4,y4,z4,w4) GSTEP(5,x5,y5,z5,w5)
        GSTEP(6,x6,y6,z6,w6) GSTEP(7,x7,y7,z7,w7)
    }
    for (; k < n; ++k) { GSTEP(0,x0,y0,z0,w0) }
#undef GSTEP
    float4 st;
    st.x = ((x0+x1)+(x2+x3)) + ((x4+x5)+(x6+x7));
    st.y = ((y0+y1)+(y2+y3)) + ((y4+y5)+(y6+y7));
    st.z = ((z0+z1)+(z2+z3)) + ((z4+z5)+(z6+z7));
    st.w = ((w0+w1)+(w2+w3)) + ((w4+w5)+(w6+w7));
    *reinterpret_cast<float4*>(&hg[(size_t)(R0 + w) * 256 + c0]) = st;
}

// ===== k_node: h_next = relu(hg @ W + b); epilogue: atomic scores | colsum part =====
#define BM 64
#define BN 64
#define BK 32
#define AP 68   // As row pitch: 16B-aligned, conflict-free staging
template <bool LAST>
__global__ __launch_bounds__(256) void k_node(
    const float* __restrict__ hin, bfu* __restrict__ hout,
    const float* __restrict__ W, const float* __restrict__ b,
    const float* __restrict__ Watt,
    float* __restrict__ snei_out, float* __restrict__ sself_out,
    float* __restrict__ part) {
    __shared__ float As[BK][AP];
    __shared__ float Ws[BK][BN];
    __shared__ float sredA[16][64];
    __shared__ float sredB[16][64];
    const int tid = threadIdx.x;
    const int tx = tid & 15;
    const int ty = tid >> 4;
    const int m0 = tx * 4, n0 = ty * 4;
    const int brow = blockIdx.x * BM;
    const int bcol = blockIdx.y * BN;
    const int sm = tid & 63;
    const int sk4 = tid >> 6;
    float acc[4][4] = {{0.f}};
    for (int k0 = 0; k0 < H; k0 += BK) {
#pragma unroll
        for (int half = 0; half < 2; ++half) {
            int kk = 4 * sk4 + 16 * half;
            float4 a = *reinterpret_cast<const float4*>(&hin[(brow + sm) * H + k0 + kk]);
            As[kk + 0][sm] = a.x;
            As[kk + 1][sm] = a.y;
            As[kk + 2][sm] = a.z;
            As[kk + 3][sm] = a.w;
        }
#pragma unroll
        for (int half = 0; half < 2; ++half) {
            int idx = tid + 256 * half;
            int kr = idx >> 4;
            int nq = idx & 15;
            float4 w = *reinterpret_cast<const float4*>(&W[(k0 + kr) * H + bcol + nq * 4]);
            *reinterpret_cast<float4*>(&Ws[kr][nq * 4]) = w;
        }
        __syncthreads();
#pragma unroll
        for (int k = 0; k < BK; ++k) {
            float4 av = *reinterpret_cast<const float4*>(&As[k][m0]);
            float4 wv = *reinterpret_cast<const float4*>(&Ws[k][n0]);
            float a[4] = {av.x, av.y, av.z, av.w};
            float w[4] = {wv.x, wv.y, wv.z, wv.w};
#pragma unroll
            for (int i = 0; i < 4; ++i)
#pragma unroll
                for (int j = 0; j < 4; ++j) acc[i][j] = fmaf(a[i], w[j], acc[i][j]);
        }
        __syncthreads();
    }
    float v[4][4];
    float4 wanv, wasv;
    if (!LAST) {
        wanv = *reinterpret_cast<const float4*>(&Watt[bcol + n0]);
        wasv = *reinterpret_cast<const float4*>(&Watt[H + bcol + n0]);
    }
#pragma unroll
    for (int i = 0; i < 4; ++i) {
#pragma unroll
        for (int j = 0; j < 4; ++j) {
            float x = acc[i][j] + b[bcol + n0 + j];
            v[i][j] = x > 0.f ? x : 0.f;
        }
        if (!LAST) {
            ushort4 o;
            o.x = f2bf(v[i][0]); o.y = f2bf(v[i][1]);
            o.z = f2bf(v[i][2]); o.w = f2bf(v[i][3]);
            *reinterpret_cast<ushort4*>(&hout[(brow + m0 + i) * H + bcol + n0]) = o;
        }
    }
    if (!LAST) {
#pragma unroll
        for (int i = 0; i < 4; ++i) {
            float pn = v[i][0]*wanv.x + v[i][1]*wanv.y + v[i][2]*wanv.z + v[i][3]*wanv.w;
            float ps = v[i][0]*wasv.x + v[i][1]*wasv.y + v[i][2]*wasv.z + v[i][3]*wasv.w;
            sredA[ty][m0 + i] = pn;
            sredB[ty][m0 + i] = ps;
        }
        __syncthreads();
        if (tid < 64) {
            float s = 0.f;
#pragma unroll
            for (int q = 0; q < 16; ++q) s += sredA[q][tid];
            atomicAdd(&snei_out[brow + tid], s);
        } else if (tid < 128) {
            int r = tid - 64;
            float s = 0.f;
#pragma unroll
            for (int q = 0; q < 16; ++q) s += sredB[q][r];
            atomicAdd(&sself_out[brow + r], s);
        }
    } else {
        float cp[4];
#pragma unroll
        for (int j = 0; j < 4; ++j) cp[j] = (v[0][j] + v[1][j]) + (v[2][j] + v[3][j]);
#pragma unroll
        for (int j = 0; j < 4; ++j) sredA[tx][n0 + j] = cp[j];
        __syncthreads();
        if (tid < 64) {
            float s = 0.f;
#pragma unroll
            for (int q = 0; q < 16; ++q) s += sredA[q][tid];
            part[blockIdx.x * 256 + bcol + tid] = s;
        }
    }
}

// ============ k_ro: entire readout in one 512-thread block ============
__global__ __launch_bounds__(512) void k_ro(
    const float* __restrict__ part, const float* __restrict__ mol,
    const bfu* __restrict__ Wt, const float* __restrict__ b1,
    const float* __restrict__ bh, const float* __restrict__ Wo,
    const float* __restrict__ bo, float* __restrict__ out) {
    __shared__ float xa[512], xb[512], red[512];
    const int t = threadIdx.x;
    {
        const int col = t & 255;
        const int r0 = (t < 256) ? 0 : 64;
        float s = 0.f;
        for (int r = 0; r < 64; ++r) s += part[(r0 + r) * 256 + col];
        red[t] = s;
    }
    __syncthreads();
    if (t < 256) xa[t] = red[t] + red[t + 256];
    else { int i = t - 256; xa[256 + i] = (i < MF) ? mol[i] : 0.f; }
    __syncthreads();
    float* xin = xa;
    float* xo = xb;
    const int w = t >> 6, l = t & 63;
#pragma unroll 1
    for (int L = 0; L < 3; ++L) {
        const bfu* Wl = Wt + L * 512 * 512;
        const float* bl = (L == 0) ? b1 : (bh + (L - 1) * RH);
#pragma unroll 4
        for (int i = 0; i < 64; ++i) {
            const int o = w * 64 + i;
            uint4 u = *reinterpret_cast<const uint4*>(&Wl[o * 512 + l * 8]);
            float4 x0 = *reinterpret_cast<const float4*>(&xin[l * 8]);
            float4 x1 = *reinterpret_cast<const float4*>(&xin[l * 8 + 4]);
            float d = x0.x * bflo(u.x) + x0.y * bfhi(u.x)
                    + x0.z * bflo(u.y) + x0.w * bfhi(u.y)
                    + x1.x * bflo(u.z) + x1.y * bfhi(u.z)
                    + x1.z * bflo(u.w) + x1.w * bfhi(u.w);
            for (int off = 32; off > 0; off >>= 1) d += __shfl_down(d, off);
            if (l == 0) {
                float vv = d + bl[o];
                xo[o] = vv > 0.f ? vv : 0.f;
            }
        }
        __syncthreads();
        float* tmp = xin; xin = xo; xo = tmp;
    }
    red[t] = xin[t] * Wo[t];
    __syncthreads();
    for (int s = 256; s > 0; s >>= 1) {
        if (t < s) red[t] += red[t + s];
        __syncthreads();
    }
    if (t == 0) out[0] = red[0] + bo[0];
}

extern "C" void kernel_launch(void* const* d_in, const int* in_sizes, int n_in,
                              void* d_out, int out_size, void* d_ws, size_t ws_size,
                              hipStream_t stream) {
    const float* A        = (const float*)d_in[0];
    const float* X        = (const float*)d_in[1];
    const float* mol      = (const float*)d_in[2];
    const float* W_in     = (const float*)d_in[3];
    const float* b_in     = (const float*)d_in[4];
    const float* W_att    = (const float*)d_in[5];
    const float* b_att    = (const float*)d_in[6];
    const float* W_node   = (const float*)d_in[7];
    const float* b_node   = (const float*)d_in[8];
    const float* W_ro_in  = (const float*)d_in[9];
    const float* b_ro_in  = (const float*)d_in[10];
    const float* W_ro_hid = (const float*)d_in[11];
    const float* b_ro_hid = (const float*)d_in[12];
    const float* W_out    = (const float*)d_in[13];
    const float* b_out    = (const float*)d_in[14];

    char* ws = (char*)d_ws;
    bfu*   hb     = (bfu*)  (ws);                        // 4 MB bf16 h
    float* hg     = (float*)(ws + 4194304);              // 8 MB fp32 aggregate
    int*   colidx = (int*)  (ws + 12582912);             // 4 MB
    int*   cnt    = (int*)  (ws + 16777216);             // 32 KB
    float* s0n    = (float*)(ws + 16809984);             // 32 KB
    float* s0s    = (float*)(ws + 16842752);             // 32 KB
    float* s1n    = (float*)(ws + 16875520);             // 32 KB
    float* s1s    = (float*)(ws + 16908288);             // 32 KB
    float* part   = (float*)(ws + 16941056);             // 128 KB (128x256)
    bfu*   Wt     = (bfu*)  (ws + 17072128);             // 1.5 MB bf16T readout W

    // front: h0+scores0 (0..255) | W_ro convert (256..271) | scan (272..2319)
    k_front<<<2320, 256, 0, stream>>>((const float4*)A, cnt, colidx,
                                      X, W_in, b_in, W_att, W_ro_in, W_ro_hid,
                                      hb, s0n, s0s, Wt);
    // depth 0
    k_agg<<<N / 4, 256, 0, stream>>>(hb, hg, cnt, colidx, s0n, s0s, b_att, s1n, s1s);
    k_node<false><<<dim3(N / BM, H / BN), 256, 0, stream>>>(
        hg, hb, W_node + 0 * H * H, b_node + 0 * H, W_att, s1n, s1s, nullptr);
    // depth 1
    k_agg<<<N / 4, 256, 0, stream>>>(hb, hg, cnt, colidx, s1n, s1s, b_att, s0n, s0s);
    k_node<false><<<dim3(N / BM, H / BN), 256, 0, stream>>>(
        hg, hb, W_node + 1 * H * H, b_node + 1 * H, W_att, s0n, s0s, nullptr);
    // depth 2 (last): colsum partials, no h store
    k_agg<<<N / 4, 256, 0, stream>>>(hb, hg, cnt, colidx, s0n, s0s, b_att, s1n, s1s);
    k_node<true><<<dim3(N / BM, H / BN), 256, 0, stream>>>(
        hg, nullptr, W_node + 2 * H * H, b_node + 2 * H, W_att, nullptr, nullptr, part);
    // fused readout
    k_ro<<<1, 512, 0, stream>>>(part, mol, Wt, b_ro_in, b_ro_hid, W_out, b_out,
                                (float*)d_out);
}